// Round 9
// baseline (222.029 us; speedup 1.0000x reference)
//
#include <hip/hip_runtime.h>

// InductionNetwork capsule routing, C=256, K=64, H=1024, 3 iterations.
// R8 post-mortem: ~11us per graph-node boundary x 13 nodes dominated the
// 216us. This version exploits  u = W^T c = alpha*(W^T W) s = alpha*G*s  and
// norm = ||W s||^2 = s.(G s): with G precomputed once, each iteration needs
// ONE GEMM (y = G s); alpha/u are computed inside routing. 8 nodes total:
//   1 prep   : routing<0> (s0) fused with W -> split-bf16 (Wb, Wt)
//   2 gemm_g : G = Wt.Wt^T (full-K strip GEMM, split-bf16, emits Gh/Gl)
//   3 yGEMM  : y = s0.G      (R8's verified gemm_split_kernel, B=G)
//   4 routing<1>: norm=s.y, u=alpha*y, b=E.u, softmax, s1
//   5 yGEMM  : y = s1.G
//   6 routing<2>: -> s2
//   7 cGEMM  : chat = s2.Wb^T (gemm_split_kernel, B=Wb)
//   8 squash_final -> out
// Split-bf16 operands everywhere (verified R6/R8, absmax 4.88e-4 = floor).
// Fallback: R3's monolithic kernel if ws too small.

using f32x4  = __attribute__((ext_vector_type(4))) float;
using f32x2  = __attribute__((ext_vector_type(2))) float;
using bf16x8 = __attribute__((ext_vector_type(8))) __bf16;
using bf16x2 = __attribute__((ext_vector_type(2))) __bf16;

struct BfPair { __bf16 hi, lo; };
__device__ inline BfPair split_bf16(float x) {
    BfPair p;
    p.hi = (__bf16)x;
    p.lo = (__bf16)(x - (float)p.hi);
    return p;
}

// ---------------- prep: routing<0> (blocks 0-255) + W split (256-511) ------
__global__ __launch_bounds__(1024) void prep_kernel(
    const float* __restrict__ enc, const float* __restrict__ W,
    __bf16* __restrict__ s_hi, __bf16* __restrict__ s_lo,
    float* __restrict__ s_f32,
    __bf16* __restrict__ Wb_hi, __bf16* __restrict__ Wb_lo,
    __bf16* __restrict__ Wt_hi, __bf16* __restrict__ Wt_lo)
{
    __shared__ float smem[16 * 1024];   // routing: spart[16][1024]; convert: tile 64x65
    const int t = threadIdx.x, lane = t & 63, w = t >> 6;   // 16 waves

    if (blockIdx.x < 256) {
        // -------- routing iter 0: d uniform -> s0 = mean_k enc[c,k,:] --------
        const int c = blockIdx.x;
        const float* E = enc + (size_t)c * 65536;
        f32x4 er[4][4];
        #pragma unroll
        for (int r = 0; r < 4; ++r) {
            const float* ek = E + (size_t)(w * 4 + r) * 1024 + lane * 8;
            er[r][0] = *(const f32x4*)(ek);
            er[r][1] = *(const f32x4*)(ek + 4);
            er[r][2] = *(const f32x4*)(ek + 512);
            er[r][3] = *(const f32x4*)(ek + 516);
        }
        #pragma unroll
        for (int q = 0; q < 4; ++q) {
            f32x4 p = {};
            #pragma unroll
            for (int r = 0; r < 4; ++r)
                #pragma unroll
                for (int j = 0; j < 4; ++j) p[j] += er[r][q][j];
            const int h = (q >> 1) * 512 + lane * 8 + (q & 1) * 4;
            p *= (1.f / 64.f);
            *(f32x4*)&smem[w * 1024 + h] = p;
        }
        __syncthreads();
        float a = 0.f;
        #pragma unroll
        for (int wv = 0; wv < 16; ++wv) a += smem[wv * 1024 + t];
        const BfPair p = split_bf16(a);
        const size_t o = (size_t)c * 1024 + t;
        s_hi[o] = p.hi; s_lo[o] = p.lo; s_f32[o] = a;
    } else {
        // -------- W -> split bf16, direct + transposed (64x64 tile) --------
        const int tb = blockIdx.x - 256;
        const int bx = tb & 15, by = tb >> 4;
        const int tx = t & 63, ty = t >> 6;     // 16 row-groups
        for (int i = ty; i < 64; i += 16) {
            const size_t idx = (size_t)(by * 64 + i) * 1024 + bx * 64 + tx;
            const float v = W[idx];
            smem[i * 65 + tx] = v;
            const BfPair p = split_bf16(v);
            Wb_hi[idx] = p.hi; Wb_lo[idx] = p.lo;
        }
        __syncthreads();
        for (int i = ty; i < 64; i += 16) {
            const size_t idx = (size_t)(bx * 64 + i) * 1024 + by * 64 + tx;
            const BfPair p = split_bf16(smem[tx * 65 + i]);
            Wt_hi[idx] = p.hi; Wt_lo[idx] = p.lo;
        }
    }
}

// ---------------- G = Wt . Wt^T (NT, M=N=K=1024, full-K strip) --------------
// 1024 waves as 256 blocks x 4. Wave gw: mt=gw>>4 (A rows mt*16..+15),
// nt=gw&15 (B rows nt*64..+63, 4 strips of 16). Epilogue splits fp32 acc
// into Gh/Gl bf16. Fragment layout verified R4/R6/R8.
__global__ __launch_bounds__(256) void gemm_g_kernel(
    const __bf16* __restrict__ Ah, const __bf16* __restrict__ Al,
    __bf16* __restrict__ Gh, __bf16* __restrict__ Gl)
{
    const int w = threadIdx.x >> 6, lane = threadIdx.x & 63;
    const int gw = blockIdx.x * 4 + w;
    const int mt = gw >> 4, nt = gw & 15;
    const int kq = (lane >> 4) * 8;
    const size_t aoff = (size_t)(mt * 16 + (lane & 15)) * 1024 + kq;
    const size_t boff = (size_t)(nt * 64 + (lane & 15)) * 1024 + kq;

    f32x4 acc0 = {}, acc1 = {}, acc2 = {}, acc3 = {};
    for (int k0 = 0; k0 < 1024; k0 += 32) {
        bf16x8 ah = *(const bf16x8*)(Ah + aoff + k0);
        bf16x8 al = *(const bf16x8*)(Al + aoff + k0);
        #pragma unroll
        for (int j = 0; j < 4; ++j) {
            const size_t bo = boff + (size_t)j * 16 * 1024 + k0;
            bf16x8 bh = *(const bf16x8*)(Ah + bo);
            bf16x8 bl = *(const bf16x8*)(Al + bo);
            f32x4& acc = (j == 0) ? acc0 : (j == 1) ? acc1 : (j == 2) ? acc2 : acc3;
            acc = __builtin_amdgcn_mfma_f32_16x16x32_bf16(ah, bh, acc, 0, 0, 0);
            acc = __builtin_amdgcn_mfma_f32_16x16x32_bf16(ah, bl, acc, 0, 0, 0);
            acc = __builtin_amdgcn_mfma_f32_16x16x32_bf16(al, bh, acc, 0, 0, 0);
        }
    }
    const int rr = (lane >> 4) * 4, colb = lane & 15;
    f32x4 accs[4] = {acc0, acc1, acc2, acc3};
    #pragma unroll
    for (int j = 0; j < 4; ++j)
        #pragma unroll
        for (int r = 0; r < 4; ++r) {
            const size_t idx = (size_t)(mt * 16 + rr + r) * 1024
                             + nt * 64 + j * 16 + colb;
            const BfPair p = split_bf16(accs[j][r]);
            Gh[idx] = p.hi; Gl[idx] = p.lo;
        }
}

// ---- split-bf16 NT GEMM, M=256, N=K=1024, splitK x2 (R8 verbatim) ----------
__global__ __launch_bounds__(256) void gemm_split_kernel(
    const __bf16* __restrict__ Ah, const __bf16* __restrict__ Al,
    const __bf16* __restrict__ Bh, const __bf16* __restrict__ Bl,
    float* __restrict__ C0, float* __restrict__ C1)
{
    const int w = threadIdx.x >> 6;
    const int gw = blockIdx.x * 4 + w;
    const int task = gw >> 1;
    const int kh   = gw & 1;
    const int mt   = task >> 6;
    const int nt   = task & 63;
    const int lane = threadIdx.x & 63;
    const int kq   = (lane >> 4) * 8 + kh * 512;
    const size_t aoff = (size_t)(mt * 16 + (lane & 15)) * 1024 + kq;
    const size_t boff = (size_t)(nt * 16 + (lane & 15)) * 1024 + kq;

    f32x4 hh = {}, hl = {}, lh = {};
    #pragma unroll 4
    for (int k0 = 0; k0 < 512; k0 += 32) {
        bf16x8 ah = *(const bf16x8*)(Ah + aoff + k0);
        bf16x8 al = *(const bf16x8*)(Al + aoff + k0);
        bf16x8 bh = *(const bf16x8*)(Bh + boff + k0);
        bf16x8 bl = *(const bf16x8*)(Bl + boff + k0);
        hh = __builtin_amdgcn_mfma_f32_16x16x32_bf16(ah, bh, hh, 0, 0, 0);
        hl = __builtin_amdgcn_mfma_f32_16x16x32_bf16(ah, bl, hl, 0, 0, 0);
        lh = __builtin_amdgcn_mfma_f32_16x16x32_bf16(al, bh, lh, 0, 0, 0);
    }
    f32x4 acc = hh + hl + lh;
    float* Cc = kh ? C1 : C0;
    const int rr = (lane >> 4) * 4, colb = lane & 15;
    #pragma unroll
    for (int r = 0; r < 4; ++r)
        Cc[(size_t)(mt * 16 + rr + r) * 1024 + nt * 16 + colb] = acc[r];
}

// ---------------- routing iters 1/2: u = alpha*y computed in-kernel ---------
// norm = s_prev . y (y = y0+y1 splitK partials); alpha = f(norm); u = alpha*y;
// b = (MODE==2 ? b_prev : 0) + E.u; softmax; s = sum_k d_k e_k.
template <int MODE>
__global__ __launch_bounds__(1024) void routing_yu_kernel(
    const float* __restrict__ enc,
    const float* __restrict__ y0, const float* __restrict__ y1,
    const float* __restrict__ s_prev, float* __restrict__ bglob,
    __bf16* __restrict__ s_hi, __bf16* __restrict__ s_lo,
    float* __restrict__ s_out)
{
    __shared__ float spart[16][1024];   // 64 KB
    __shared__ float u_s[1024];
    __shared__ float b_s[64];
    __shared__ float d_s[64];
    __shared__ float red_s[16];

    const int t = threadIdx.x, lane = t & 63, w = t >> 6;   // 16 waves
    const int c = blockIdx.x;
    const float* E = enc + (size_t)c * 65536;

    // enc rows w*4..w*4+3 into registers (issued early for latency)
    f32x4 er[4][4];
    #pragma unroll
    for (int r = 0; r < 4; ++r) {
        const float* ek = E + (size_t)(w * 4 + r) * 1024 + lane * 8;
        er[r][0] = *(const f32x4*)(ek);
        er[r][1] = *(const f32x4*)(ek + 4);
        er[r][2] = *(const f32x4*)(ek + 512);
        er[r][3] = *(const f32x4*)(ek + 516);
    }

    // norm = sum_h s_prev[h]*y[h]; thread t owns h=t
    const size_t o = (size_t)c * 1024 + t;
    const float yv = y0[o] + y1[o];
    float prod = s_prev[o] * yv;
    #pragma unroll
    for (int off = 32; off; off >>= 1) prod += __shfl_xor(prod, off, 64);
    if (lane == 0) red_s[w] = prod;
    __syncthreads();
    float norm = 0.f;
    #pragma unroll
    for (int i = 0; i < 16; ++i) norm += red_s[i];
    const float alpha = norm / ((1.f + norm) * sqrtf(norm) + 1e-30f);
    u_s[t] = alpha * yv;
    __syncthreads();

    // b-update from u_s
    {
        f32x4 uf[4];
        #pragma unroll
        for (int q = 0; q < 4; ++q)
            uf[q] = *(const f32x4*)&u_s[(q >> 1) * 512 + lane * 8 + (q & 1) * 4];
        #pragma unroll
        for (int r = 0; r < 4; ++r) {
            float sum = 0.f;
            #pragma unroll
            for (int q = 0; q < 4; ++q)
                #pragma unroll
                for (int j = 0; j < 4; ++j)
                    sum += er[r][q][j] * uf[q][j];
            #pragma unroll
            for (int off = 32; off; off >>= 1) sum += __shfl_xor(sum, off, 64);
            if (lane == 0) {
                const int k = w * 4 + r;
                const float bv = (MODE == 2) ? (bglob[c * 64 + k] + sum) : sum;
                bglob[c * 64 + k] = bv;
                b_s[k] = bv;
            }
        }
    }
    __syncthreads();

    if (t < 64) {
        float bv = b_s[t], m = bv;
        #pragma unroll
        for (int off = 32; off; off >>= 1) m = fmaxf(m, __shfl_xor(m, off, 64));
        const float e = expf(bv - m);
        float sm = e;
        #pragma unroll
        for (int off = 32; off; off >>= 1) sm += __shfl_xor(sm, off, 64);
        d_s[t] = e / sm;
    }
    __syncthreads();

    #pragma unroll
    for (int q = 0; q < 4; ++q) {
        f32x4 p = {};
        #pragma unroll
        for (int r = 0; r < 4; ++r) {
            const float dk = d_s[w * 4 + r];
            #pragma unroll
            for (int j = 0; j < 4; ++j) p[j] += dk * er[r][q][j];
        }
        const int h = (q >> 1) * 512 + lane * 8 + (q & 1) * 4;
        *(f32x4*)&spart[w][h] = p;
    }
    __syncthreads();

    {
        float a = 0.f;
        #pragma unroll
        for (int wv = 0; wv < 16; ++wv) a += spart[wv][t];
        const BfPair p = split_bf16(a);
        s_hi[o] = p.hi; s_lo[o] = p.lo; s_out[o] = a;
    }
}

// ---------------- final squash -> out ---------------------------------------
__global__ __launch_bounds__(256) void squash_final_kernel(
    const float* __restrict__ chat0, const float* __restrict__ chat1,
    float* __restrict__ outp)
{
    __shared__ float wsum[4];
    const int c = blockIdx.x, t = threadIdx.x;
    const int lane = t & 63, w = t >> 6;
    const size_t o = (size_t)c * 1024 + t * 4;
    f32x4 v = *(const f32x4*)(chat0 + o) + *(const f32x4*)(chat1 + o);
    float ss = v[0]*v[0] + v[1]*v[1] + v[2]*v[2] + v[3]*v[3];
    #pragma unroll
    for (int off = 32; off; off >>= 1) ss += __shfl_xor(ss, off, 64);
    if (lane == 0) wsum[w] = ss;
    __syncthreads();
    const float norm = wsum[0] + wsum[1] + wsum[2] + wsum[3];
    const float scale = norm / ((1.f + norm) * sqrtf(norm) + 1e-30f);
    *(f32x4*)(outp + o) = v * scale;
}

// ---------------- fallback: R3's proven monolithic fp32 kernel --------------
__global__ __launch_bounds__(512) void fallback_kernel(
    const float* __restrict__ enc, const float* __restrict__ W,
    float* __restrict__ outp)
{
    __shared__ float u_s[1024], s_s[1024], c_s[1024], chat_s[1024];
    __shared__ float b_s[64], d_s[64], red_s[8];
    const int t = threadIdx.x, lane = t & 63, w = t >> 6;
    const float* erow = enc + (size_t)blockIdx.x * 65536;

    if (t < 64) b_s[t] = 0.f;
    __syncthreads();

    for (int it = 0; it < 3; ++it) {
        if (it > 0) {
            f32x4 uf[4];
            #pragma unroll
            for (int q = 0; q < 2; ++q) {
                uf[2*q]   = *(const f32x4*)&u_s[q*512 + lane*8];
                uf[2*q+1] = *(const f32x4*)&u_s[q*512 + lane*8 + 4];
            }
            for (int r = 0; r < 8; ++r) {
                const int k = w * 8 + r;
                const float* ek = erow + (size_t)k * 1024;
                float sum = 0.f;
                #pragma unroll
                for (int q = 0; q < 2; ++q) {
                    f32x4 e0 = *(const f32x4*)(ek + q*512 + lane*8);
                    f32x4 e1 = *(const f32x4*)(ek + q*512 + lane*8 + 4);
                    #pragma unroll
                    for (int j = 0; j < 4; ++j) {
                        sum += e0[j] * uf[2*q][j];
                        sum += e1[j] * uf[2*q+1][j];
                    }
                }
                #pragma unroll
                for (int off = 32; off; off >>= 1) sum += __shfl_xor(sum, off, 64);
                if (lane == 0) b_s[k] += sum;
            }
            __syncthreads();
        }
        if (t < 64) {
            float bv = b_s[t], m = bv;
            #pragma unroll
            for (int off = 32; off; off >>= 1) m = fmaxf(m, __shfl_xor(m, off, 64));
            float e = expf(bv - m), sm = e;
            #pragma unroll
            for (int off = 32; off; off >>= 1) sm += __shfl_xor(sm, off, 64);
            d_s[t] = e / sm;
        }
        __syncthreads();
        {
            const int h0 = t * 2;
            float a0 = 0.f, a1 = 0.f;
            for (int k = 0; k < 64; ++k) {
                f32x2 ev = *(const f32x2*)(erow + (size_t)k * 1024 + h0);
                a0 += d_s[k] * ev[0]; a1 += d_s[k] * ev[1];
            }
            s_s[h0] = a0; s_s[h0+1] = a1;
        }
        __syncthreads();
        {
            f32x4 sf[4];
            #pragma unroll
            for (int q = 0; q < 2; ++q) {
                sf[2*q]   = *(const f32x4*)&s_s[q*512 + lane*8];
                sf[2*q+1] = *(const f32x4*)&s_s[q*512 + lane*8 + 4];
            }
            for (int r = 0; r < 128; ++r) {
                const int d = w * 128 + r;
                const float* wr = W + (size_t)d * 1024;
                float sum = 0.f;
                #pragma unroll
                for (int q = 0; q < 2; ++q) {
                    f32x4 w0 = *(const f32x4*)(wr + q*512 + lane*8);
                    f32x4 w1 = *(const f32x4*)(wr + q*512 + lane*8 + 4);
                    #pragma unroll
                    for (int j = 0; j < 4; ++j) {
                        sum += w0[j] * sf[2*q][j];
                        sum += w1[j] * sf[2*q+1][j];
                    }
                }
                #pragma unroll
                for (int off = 32; off; off >>= 1) sum += __shfl_xor(sum, off, 64);
                if (lane == 0) chat_s[d] = sum;
            }
        }
        __syncthreads();
        {
            const int h0 = t * 2;
            float v0 = chat_s[h0], v1 = chat_s[h0+1];
            float ss = v0*v0 + v1*v1;
            #pragma unroll
            for (int off = 32; off; off >>= 1) ss += __shfl_xor(ss, off, 64);
            if (lane == 0) red_s[w] = ss;
            __syncthreads();
            float norm = 0.f;
            #pragma unroll
            for (int i = 0; i < 8; ++i) norm += red_s[i];
            const float scale = norm / ((1.f + norm) * sqrtf(norm) + 1e-30f);
            c_s[h0] = v0 * scale; c_s[h0+1] = v1 * scale;
        }
        __syncthreads();
        if (it < 2) {
            const int h0 = t * 2;
            float uu0 = 0.f, uu1 = 0.f;
            for (int d = 0; d < 1024; ++d) {
                f32x2 wv = *(const f32x2*)(W + (size_t)d * 1024 + h0);
                uu0 += c_s[d] * wv[0]; uu1 += c_s[d] * wv[1];
            }
            u_s[h0] = uu0; u_s[h0+1] = uu1;
        } else {
            const int h0 = t * 2;
            f32x2 ov; ov[0] = c_s[h0]; ov[1] = c_s[h0+1];
            *(f32x2*)(outp + (size_t)blockIdx.x * 1024 + h0) = ov;
        }
        __syncthreads();
    }
}

extern "C" void kernel_launch(void* const* d_in, const int* in_sizes, int n_in,
                              void* d_out, int out_size, void* d_ws, size_t ws_size,
                              hipStream_t stream)
{
    const float* enc = (const float*)d_in[0];   // [256,64,1024] fp32
    const float* W   = (const float*)d_in[1];   // [1024,1024]   fp32
    float* outp = (float*)d_out;                // [256,1024]    fp32
    (void)in_sizes; (void)n_in; (void)out_size;

    // ws layout (19.06 MB)
    char* ws = (char*)d_ws;
    float*  b      = (float*) (ws + 0x0000000);  //   64 KB [256,64]
    __bf16* s_hi   = (__bf16*)(ws + 0x0010000);  //  512 KB
    __bf16* s_lo   = (__bf16*)(ws + 0x0090000);  //  512 KB
    float*  s_f32a = (float*) (ws + 0x0110000);  //    1 MB
    float*  s_f32b = (float*) (ws + 0x0210000);  //    1 MB
    float*  y0     = (float*) (ws + 0x0310000);  //    1 MB
    float*  y1     = (float*) (ws + 0x0410000);  //    1 MB
    float*  chat0  = (float*) (ws + 0x0510000);  //    1 MB
    float*  chat1  = (float*) (ws + 0x0610000);  //    1 MB
    __bf16* Wb_hi  = (__bf16*)(ws + 0x0710000);  //    2 MB [d,h]
    __bf16* Wb_lo  = (__bf16*)(ws + 0x0910000);  //    2 MB [d,h]
    __bf16* Wt_hi  = (__bf16*)(ws + 0x0B10000);  //    2 MB [h,d]
    __bf16* Wt_lo  = (__bf16*)(ws + 0x0D10000);  //    2 MB [h,d]
    __bf16* Gh     = (__bf16*)(ws + 0x0F10000);  //    2 MB [1024,1024]
    __bf16* Gl     = (__bf16*)(ws + 0x1110000);  //    2 MB

    if (ws_size < 0x1310000) {
        fallback_kernel<<<256, 512, 0, stream>>>(enc, W, outp);
        return;
    }

    // 1. routing<0> + W split
    prep_kernel<<<512, 1024, 0, stream>>>(enc, W, s_hi, s_lo, s_f32a,
                                          Wb_hi, Wb_lo, Wt_hi, Wt_lo);
    // 2. G = W^T W  (= Wt . Wt^T)
    gemm_g_kernel<<<256, 256, 0, stream>>>(Wt_hi, Wt_lo, Gh, Gl);
    // 3. y = s0 . G
    gemm_split_kernel<<<512, 256, 0, stream>>>(s_hi, s_lo, Gh, Gl, y0, y1);
    // 4. routing<1>: u=alpha*y in-kernel, b = E.u, s1
    routing_yu_kernel<1><<<256, 1024, 0, stream>>>(enc, y0, y1, s_f32a, b,
                                                   s_hi, s_lo, s_f32b);
    // 5. y = s1 . G
    gemm_split_kernel<<<512, 256, 0, stream>>>(s_hi, s_lo, Gh, Gl, y0, y1);
    // 6. routing<2>: b += E.u, s2
    routing_yu_kernel<2><<<256, 1024, 0, stream>>>(enc, y0, y1, s_f32b, b,
                                                   s_hi, s_lo, s_f32a);
    // 7. chat = s2 . W^T
    gemm_split_kernel<<<512, 256, 0, stream>>>(s_hi, s_lo, Wb_hi, Wb_lo,
                                               chat0, chat1);
    // 8. squash -> out
    squash_final_kernel<<<256, 256, 0, stream>>>(chat0, chat1, outp);
}